// Round 9
// baseline (59.313 us; speedup 1.0000x reference)
//
#include <hip/hip_runtime.h>
#include <hip/hip_bf16.h>

// Local (trunked) attention, MI355X gfx950.
// B=1, H=16, N=16384, d=64 fp32; 32-query trunks x 128-key window, pad_left=48.
// Block = 4 waves = 4 consecutive trunks of one head. Only V is LDS-staged
// (224-row window union, 4x16 subtiles consumed via ds_read_b64_tr_b16);
// K is read directly from global f32 in the S^T loop (lane = key-row is
// naturally coalesced and L2/L3-warm). 28.7 KB LDS -> 5 blocks/CU.
// Swapped-QK^T 32x32 MFMA structure, per-lane softmax, P normalized in the
// in-register pack (cvt_pkrtz + permlane32_swap).

typedef _Float16 f16x8 __attribute__((ext_vector_type(8)));
typedef _Float16 f16x4 __attribute__((ext_vector_type(4)));
typedef float f32x16 __attribute__((ext_vector_type(16)));
typedef unsigned int u32;
typedef u32 u32x4 __attribute__((ext_vector_type(4)));

#define NSEQ   16384
#define DHEAD  64
#define LOG2E  1.44269504088896340736f
#define TRB    4                 // trunks per block
#define BQ     (TRB * 32)        // 128 queries per block
#define WROWS  (BQ + 96)         // 224 staged V rows
#define VBYTES (WROWS * 128)     // 28672 (14 x 2KB key-16 blocks)

__device__ __forceinline__ u32 pk2(float a, float b) {
  auto h2 = __builtin_amdgcn_cvt_pkrtz(a, b);
  return __builtin_bit_cast(u32, h2);
}

__device__ __forceinline__ void plswap(u32& a, u32& b) {
#if __has_builtin(__builtin_amdgcn_permlane32_swap)
  typedef u32 u32x2 __attribute__((ext_vector_type(2)));
  u32x2 r = __builtin_amdgcn_permlane32_swap(a, b, false, false);
  a = r[0]; b = r[1];
#else
  const int hi = (threadIdx.x & 63) >> 5;
  u32 sa = (u32)__shfl_xor((int)a, 32);
  u32 sb = (u32)__shfl_xor((int)b, 32);
  u32 na = hi ? sb : a;
  u32 nb = hi ? b : sa;
  a = na; b = nb;
#endif
}

// 8 transpose-reads (one 32-key tile x full d), one wait.
// va = Vc + block16(kt,b=0)*2048 + lane*8.
// t[0..3] = b-half 0: {d0..31 lo, d0..31 hi, d32..63 lo, d32..63 hi}
// t[4..7] = b-half 1 (next 16 keys), same order.
__device__ __forceinline__ void tr8(u32 va, f16x4 (&t)[8]) {
  asm volatile("ds_read_b64_tr_b16 %0, %8 offset:0\n\t"
               "ds_read_b64_tr_b16 %1, %8 offset:1024\n\t"
               "ds_read_b64_tr_b16 %2, %8 offset:512\n\t"
               "ds_read_b64_tr_b16 %3, %8 offset:1536\n\t"
               "ds_read_b64_tr_b16 %4, %8 offset:2048\n\t"
               "ds_read_b64_tr_b16 %5, %8 offset:3072\n\t"
               "ds_read_b64_tr_b16 %6, %8 offset:2560\n\t"
               "ds_read_b64_tr_b16 %7, %8 offset:3584\n\t"
               "s_waitcnt lgkmcnt(0)"
               : "=&v"(t[0]), "=&v"(t[1]), "=&v"(t[2]), "=&v"(t[3]),
                 "=&v"(t[4]), "=&v"(t[5]), "=&v"(t[6]), "=&v"(t[7])
               : "v"(va));
  __builtin_amdgcn_sched_barrier(0);
}

// Stage V (224 rows x 64 f32 -> f16) into 4x16 subtiles matching tr8:
// within each 2KB key-16 block, subtile idx =
//   ((kk>>2)&1)*8 + (dh>>1)*4 + ((kk>>3)&1)*2 + (dh&1),  kk=r&15, dh=d>>4.
__device__ __forceinline__ void stageV(const float* __restrict__ src, int grow0,
                                       char* __restrict__ dst, int tid) {
  const int rsub = tid >> 3;          // 0..31
  const int c8   = (tid & 7) * 8;     // f32 col
  const int dh   = c8 >> 4;
  #pragma unroll
  for (int it = 0; it < 7; ++it) {
    const int r = it * 32 + rsub;
    const int g = min(max(grow0 + r, 0), NSEQ - 1);   // clamp; masked in S
    const float* p = src + (size_t)g * DHEAD + c8;
    const float4 a = *reinterpret_cast<const float4*>(p);
    const float4 b = *reinterpret_cast<const float4*>(p + 4);
    const u32x4 w = {pk2(a.x, a.y), pk2(a.z, a.w), pk2(b.x, b.y), pk2(b.z, b.w)};
    const int idx = ((r >> 2) & 1) * 8 + (dh >> 1) * 4 + ((r >> 3) & 1) * 2 + (dh & 1);
    const int addr = (r >> 4) * 2048 + idx * 128 + (r & 3) * 32 + (c8 & 15) * 2;
    *reinterpret_cast<u32x4*>(dst + addr) = w;
  }
}

__global__ __launch_bounds__(256, 3) void local_attn_kernel(
    const float* __restrict__ q, const float* __restrict__ k,
    const float* __restrict__ v, float* __restrict__ out) {
  __shared__ __align__(128) char Vc[VBYTES];   // 28,672 B (V only)

  const int tid  = threadIdx.x;
  const int wave = tid >> 6;
  const int lane = tid & 63;
  const int l31  = lane & 31;
  const int hi   = lane >> 5;

  int bid = blockIdx.x;
  bid = (bid & 7) * 256 + (bid >> 3);      // XCD swizzle (2048 % 8 == 0)
  const int h   = bid >> 7;                // head
  const int q0b = (bid & 127) << 7;        // block's first query row
  const int kg0 = q0b - 48;                // global row of V LDS row 0
  const int q0  = q0b + wave * 32;         // this wave's trunk
  const int kb0 = q0 - 48;                 // wave's window start

  const float* __restrict__ qh = q + (size_t)h * NSEQ * DHEAD;
  const float* __restrict__ kh = k + (size_t)h * NSEQ * DHEAD;
  const float* __restrict__ vh = v + (size_t)h * NSEQ * DHEAD;

  // ---- Q raw loads issued before staging (latency hides under stage) ----
  float4 qr[4][2];
  #pragma unroll
  for (int ks = 0; ks < 4; ++ks) {
    const float* p = qh + (size_t)(q0 + l31) * DHEAD + ks * 16 + hi * 8;
    qr[ks][0] = *reinterpret_cast<const float4*>(p);
    qr[ks][1] = *reinterpret_cast<const float4*>(p + 4);
  }

  // ---- cooperative V staging --------------------------------------------
  stageV(vh, kg0, Vc, tid);

  // ---- Q -> f16 fragments (log2e-scaled), frees qr ----------------------
  f16x8 qf[4];
  #pragma unroll
  for (int ks = 0; ks < 4; ++ks) {
    qf[ks][0] = (_Float16)(qr[ks][0].x * LOG2E); qf[ks][1] = (_Float16)(qr[ks][0].y * LOG2E);
    qf[ks][2] = (_Float16)(qr[ks][0].z * LOG2E); qf[ks][3] = (_Float16)(qr[ks][0].w * LOG2E);
    qf[ks][4] = (_Float16)(qr[ks][1].x * LOG2E); qf[ks][5] = (_Float16)(qr[ks][1].y * LOG2E);
    qf[ks][6] = (_Float16)(qr[ks][1].z * LOG2E); qf[ks][7] = (_Float16)(qr[ks][1].w * LOG2E);
  }

  __syncthreads();

  // ---- S^T = K Q^T, K direct from global (lane = key-row, coalesced) ----
  // D[m=key][n=q]: col = lane&31 = q, row = (r&3)+8*(r>>2)+4*hi (+32*kt)
  f32x16 sacc[4] = {};
  #pragma unroll
  for (int kt = 0; kt < 4; ++kt) {
    const int krow = min(max(kb0 + kt * 32 + l31, 0), NSEQ - 1);
    const float* kp = kh + (size_t)krow * DHEAD + hi * 8;
    float4 kr[4][2];
    #pragma unroll
    for (int ks = 0; ks < 4; ++ks) {
      kr[ks][0] = *reinterpret_cast<const float4*>(kp + ks * 16);
      kr[ks][1] = *reinterpret_cast<const float4*>(kp + ks * 16 + 4);
    }
    #pragma unroll
    for (int ks = 0; ks < 4; ++ks) {
      union { f16x8 f; u32 u[4]; } kf;
      kf.u[0] = pk2(kr[ks][0].x, kr[ks][0].y);
      kf.u[1] = pk2(kr[ks][0].z, kr[ks][0].w);
      kf.u[2] = pk2(kr[ks][1].x, kr[ks][1].y);
      kf.u[3] = pk2(kr[ks][1].z, kr[ks][1].w);
      sacc[kt] = __builtin_amdgcn_mfma_f32_32x32x16_f16(kf.f, qf[ks], sacc[kt], 0, 0, 0);
    }
  }

  // ---- mask invalid keys (edge trunks only) -----------------------------
  if (q0 < 48 || q0 > NSEQ - 80) {
    #pragma unroll
    for (int kt = 0; kt < 4; ++kt)
      #pragma unroll
      for (int r = 0; r < 16; ++r) {
        const int key = kb0 + kt * 32 + (r & 3) + 8 * (r >> 2) + 4 * hi;
        if ((unsigned)key >= (unsigned)NSEQ) sacc[kt][r] = -1e30f;
      }
  }

  // ---- per-lane softmax over 128 keys (base-2 domain) -------------------
  float mx = -1e30f;
  #pragma unroll
  for (int kt = 0; kt < 4; ++kt)
    #pragma unroll
    for (int r = 0; r < 16; ++r) mx = fmaxf(mx, sacc[kt][r]);
  mx = fmaxf(mx, __shfl_xor(mx, 32));
  float sum = 0.f;
  #pragma unroll
  for (int kt = 0; kt < 4; ++kt)
    #pragma unroll
    for (int r = 0; r < 16; ++r) {
      const float p = exp2f(sacc[kt][r] - mx);
      sacc[kt][r] = p;
      sum += p;
    }
  sum += __shfl_xor(sum, 32);
  const float inv = 1.0f / sum;

  // ---- P -> A-fragments in-register, normalized HERE --------------------
  // (lane col = query only in the S^T phase; after PV lanes mean d-columns)
  f16x8 pa[4][2];
  #pragma unroll
  for (int kt = 0; kt < 4; ++kt) {
    u32 pk[8];
    #pragma unroll
    for (int c = 0; c < 8; ++c)
      pk[c] = pk2(sacc[kt][2 * c] * inv, sacc[kt][2 * c + 1] * inv);
    plswap(pk[0], pk[2]); plswap(pk[1], pk[3]);
    plswap(pk[4], pk[6]); plswap(pk[5], pk[7]);
    union { f16x8 f; u32 u[4]; } f0, f1;
    f0.u[0] = pk[0]; f0.u[1] = pk[1]; f0.u[2] = pk[2]; f0.u[3] = pk[3];
    f1.u[0] = pk[4]; f1.u[1] = pk[5]; f1.u[2] = pk[6]; f1.u[3] = pk[7];
    pa[kt][0] = f0.f;
    pa[kt][1] = f1.f;
  }

  // ---- O = P V  (32 x 64), V via hardware transpose reads ---------------
  const u32 vb = (u32)(size_t)(&Vc[0]) + (u32)(lane * 8);
  f32x16 oacc[2] = {};
  #pragma unroll
  for (int kt = 0; kt < 4; ++kt) {
    f16x4 t[8];
    tr8(vb + (u32)(2 * (wave + kt) * 2048), t);
    union { f16x8 f; f16x4 h[2]; } b00, b01, b10, b11;
    b00.h[0] = t[0]; b00.h[1] = t[1];   // b-half 0, d 0..31
    b01.h[0] = t[2]; b01.h[1] = t[3];   // b-half 0, d 32..63
    b10.h[0] = t[4]; b10.h[1] = t[5];   // b-half 1, d 0..31
    b11.h[0] = t[6]; b11.h[1] = t[7];   // b-half 1, d 32..63
    oacc[0] = __builtin_amdgcn_mfma_f32_32x32x16_f16(pa[kt][0], b00.f, oacc[0], 0, 0, 0);
    oacc[1] = __builtin_amdgcn_mfma_f32_32x32x16_f16(pa[kt][0], b01.f, oacc[1], 0, 0, 0);
    oacc[0] = __builtin_amdgcn_mfma_f32_32x32x16_f16(pa[kt][1], b10.f, oacc[0], 0, 0, 0);
    oacc[1] = __builtin_amdgcn_mfma_f32_32x32x16_f16(pa[kt][1], b11.f, oacc[1], 0, 0, 0);
  }

  // ---- store O (row = query = crow(r,hi); col = lane = d) ---------------
  float* __restrict__ oh = out + (size_t)h * NSEQ * DHEAD;
  #pragma unroll
  for (int r = 0; r < 16; ++r) {
    const int row = q0 + (r & 3) + 8 * (r >> 2) + 4 * hi;
    float* po = oh + (size_t)row * DHEAD + l31;
    po[0]  = oacc[0][r];
    po[32] = oacc[1][r];
  }
}

extern "C" void kernel_launch(void* const* d_in, const int* in_sizes, int n_in,
                              void* d_out, int out_size, void* d_ws, size_t ws_size,
                              hipStream_t stream) {
  const float* q = (const float*)d_in[0];
  const float* k = (const float*)d_in[1];
  const float* v = (const float*)d_in[2];
  float* out = (float*)d_out;
  dim3 grid(2048), block(256);   // block = 4 consecutive trunks of one head
  hipLaunchKernelGGL(local_attn_kernel, grid, block, 0, stream, q, k, v, out);
}

// Round 10
// 50.398 us; speedup vs baseline: 1.1769x; 1.1769x over previous
//
#include <hip/hip_runtime.h>
#include <hip/hip_bf16.h>

// Local (trunked) attention, MI355X gfx950.
// B=1, H=16, N=16384, d=64 fp32; 32-query trunks x 128-key window, pad_left=48.
// Persistent-block pipeline: 512 blocks (2/CU), each block = 4 waves handling
// 4 consecutive 128-query tiles of one head. K/V staged as f16 in a 256-row
// LDS ring (64 KB total): prologue stages 224 rows; per tile, the next 128
// rows are loaded to regs BEFORE compute (HBM latency hides under MFMA/softmax)
// and written to LDS after a barrier. K: row-major XOR-swizzled ds_read_b128;
// V: 4x16 subtiles via ds_read_b64_tr_b16. Swapped-QK^T 32x32 MFMA, per-lane
// softmax, P normalized in the in-register pack (cvt_pkrtz + permlane32_swap).

typedef _Float16 f16x8 __attribute__((ext_vector_type(8)));
typedef _Float16 f16x4 __attribute__((ext_vector_type(4)));
typedef float f32x16 __attribute__((ext_vector_type(16)));
typedef unsigned int u32;
typedef u32 u32x4 __attribute__((ext_vector_type(4)));

#define NSEQ   16384
#define DHEAD  64
#define LOG2E  1.44269504088896340736f
#define RMASK  255               // 256-slot row ring

__device__ __forceinline__ int swz(int r) {
  return ((r & 7) << 4) | ((r & 8) << 3);
}

__device__ __forceinline__ u32 pk2(float a, float b) {
  auto h2 = __builtin_amdgcn_cvt_pkrtz(a, b);
  return __builtin_bit_cast(u32, h2);
}

__device__ __forceinline__ void plswap(u32& a, u32& b) {
#if __has_builtin(__builtin_amdgcn_permlane32_swap)
  typedef u32 u32x2 __attribute__((ext_vector_type(2)));
  u32x2 r = __builtin_amdgcn_permlane32_swap(a, b, false, false);
  a = r[0]; b = r[1];
#else
  const int hi = (threadIdx.x & 63) >> 5;
  u32 sa = (u32)__shfl_xor((int)a, 32);
  u32 sb = (u32)__shfl_xor((int)b, 32);
  u32 na = hi ? sb : a;
  u32 nb = hi ? b : sa;
  a = na; b = nb;
#endif
}

// 8 transpose-reads (one 32-key tile x full d), one wait.
// va = Vc + block16pair_base*2048 + lane*8.
__device__ __forceinline__ void tr8(u32 va, f16x4 (&t)[8]) {
  asm volatile("ds_read_b64_tr_b16 %0, %8 offset:0\n\t"
               "ds_read_b64_tr_b16 %1, %8 offset:1024\n\t"
               "ds_read_b64_tr_b16 %2, %8 offset:512\n\t"
               "ds_read_b64_tr_b16 %3, %8 offset:1536\n\t"
               "ds_read_b64_tr_b16 %4, %8 offset:2048\n\t"
               "ds_read_b64_tr_b16 %5, %8 offset:3072\n\t"
               "ds_read_b64_tr_b16 %6, %8 offset:2560\n\t"
               "ds_read_b64_tr_b16 %7, %8 offset:3584\n\t"
               "s_waitcnt lgkmcnt(0)"
               : "=&v"(t[0]), "=&v"(t[1]), "=&v"(t[2]), "=&v"(t[3]),
                 "=&v"(t[4]), "=&v"(t[5]), "=&v"(t[6]), "=&v"(t[7])
               : "v"(va));
  __builtin_amdgcn_sched_barrier(0);
}

// V subtile address within the ring (slot-based; matches tr8's delivery).
__device__ __forceinline__ int vaddr(int slot, int c8) {
  const int dh = c8 >> 4;
  const int idx = ((slot >> 2) & 1) * 8 + (dh >> 1) * 4 + ((slot >> 3) & 1) * 2 + (dh & 1);
  return (slot >> 4) * 2048 + idx * 128 + (slot & 3) * 32 + (c8 & 15) * 2;
}

__global__ __launch_bounds__(256, 2) void local_attn_kernel(
    const float* __restrict__ q, const float* __restrict__ k,
    const float* __restrict__ v, float* __restrict__ out) {
  __shared__ __align__(128) char smem[65536];   // K ring 32 KB + V ring 32 KB
  char* const Kc = smem;
  char* const Vc = smem + 32768;

  const int tid  = threadIdx.x;
  const int wave = tid >> 6;
  const int lane = tid & 63;
  const int l31  = lane & 31;
  const int hi   = lane >> 5;
  const int rsub = tid >> 3;          // 0..31 (stage row-sub)
  const int c8   = (tid & 7) * 8;     // stage f32 col

  int bid = blockIdx.x;
  bid = (bid & 7) * 64 + (bid >> 3);  // XCD swizzle (512 = 8*64, bijective)
  const int h   = bid >> 5;           // head
  const int q0b = (bid & 31) << 9;    // block's first query row (512-query span)
  const int kg0 = q0b - 48;           // global row of ring slot 0

  const float* __restrict__ qh = q + (size_t)h * NSEQ * DHEAD;
  const float* __restrict__ kh = k + (size_t)h * NSEQ * DHEAD;
  const float* __restrict__ vh = v + (size_t)h * NSEQ * DHEAD;
  float* __restrict__ oh = out + (size_t)h * NSEQ * DHEAD;

  // ---- prologue: stage rows 0..223 (tile 0's window) --------------------
  #pragma unroll
  for (int it = 0; it < 7; ++it) {
    const int r = it * 32 + rsub;
    const int g = min(max(kg0 + r, 0), NSEQ - 1);
    const float* pk_ = kh + (size_t)g * DHEAD + c8;
    const float4 ka = *reinterpret_cast<const float4*>(pk_);
    const float4 kb = *reinterpret_cast<const float4*>(pk_ + 4);
    const float* pv_ = vh + (size_t)g * DHEAD + c8;
    const float4 va_ = *reinterpret_cast<const float4*>(pv_);
    const float4 vb_ = *reinterpret_cast<const float4*>(pv_ + 4);
    const u32x4 wk = {pk2(ka.x, ka.y), pk2(ka.z, ka.w), pk2(kb.x, kb.y), pk2(kb.z, kb.w)};
    *reinterpret_cast<u32x4*>(Kc + ((r * 128 + c8 * 2) ^ swz(r))) = wk;
    const u32x4 wv = {pk2(va_.x, va_.y), pk2(va_.z, va_.w), pk2(vb_.x, vb_.y), pk2(vb_.z, vb_.w)};
    *reinterpret_cast<u32x4*>(Vc + vaddr(r, c8)) = wv;
  }

  // ---- Q for tile 0 ------------------------------------------------------
  float4 qrA[4][2];
  #pragma unroll
  for (int ks = 0; ks < 4; ++ks) {
    const float* p = qh + (size_t)(q0b + wave * 32 + l31) * DHEAD + ks * 16 + hi * 8;
    qrA[ks][0] = *reinterpret_cast<const float4*>(p);
    qrA[ks][1] = *reinterpret_cast<const float4*>(p + 4);
  }

  __syncthreads();

  // ---- 4-tile pipeline ---------------------------------------------------
  #pragma unroll
  for (int t = 0; t < 4; ++t) {
    const int q0  = q0b + t * 128 + wave * 32;   // this wave's trunk
    const int kb0 = q0 - 48;

    // -- issue next tile's stage loads + Q loads (fly during compute) ----
    float4 sk[4][2], sv[4][2], qrB[4][2];
    const int rbase = 224 + 128 * t;
    if (t < 3) {
      #pragma unroll
      for (int it = 0; it < 4; ++it) {
        const int r = rbase + it * 32 + rsub;
        const int g = min(max(kg0 + r, 0), NSEQ - 1);
        const float* pk_ = kh + (size_t)g * DHEAD + c8;
        sk[it][0] = *reinterpret_cast<const float4*>(pk_);
        sk[it][1] = *reinterpret_cast<const float4*>(pk_ + 4);
        const float* pv_ = vh + (size_t)g * DHEAD + c8;
        sv[it][0] = *reinterpret_cast<const float4*>(pv_);
        sv[it][1] = *reinterpret_cast<const float4*>(pv_ + 4);
      }
      #pragma unroll
      for (int ks = 0; ks < 4; ++ks) {
        const float* p = qh + (size_t)(q0 + 128 + l31) * DHEAD + ks * 16 + hi * 8;
        qrB[ks][0] = *reinterpret_cast<const float4*>(p);
        qrB[ks][1] = *reinterpret_cast<const float4*>(p + 4);
      }
    }

    // -- Q -> f16 fragments (log2e-scaled) -------------------------------
    f16x8 qf[4];
    #pragma unroll
    for (int ks = 0; ks < 4; ++ks) {
      qf[ks][0] = (_Float16)(qrA[ks][0].x * LOG2E); qf[ks][1] = (_Float16)(qrA[ks][0].y * LOG2E);
      qf[ks][2] = (_Float16)(qrA[ks][0].z * LOG2E); qf[ks][3] = (_Float16)(qrA[ks][0].w * LOG2E);
      qf[ks][4] = (_Float16)(qrA[ks][1].x * LOG2E); qf[ks][5] = (_Float16)(qrA[ks][1].y * LOG2E);
      qf[ks][6] = (_Float16)(qrA[ks][1].z * LOG2E); qf[ks][7] = (_Float16)(qrA[ks][1].w * LOG2E);
    }

    // -- S^T = K Q^T (128 keys x 32 queries), K from ring ----------------
    f32x16 sacc[4] = {};
    #pragma unroll
    for (int ks = 0; ks < 4; ++ks) {
      #pragma unroll
      for (int kt = 0; kt < 4; ++kt) {
        const int slot = (t * 128 + (wave + kt) * 32 + l31) & RMASK;
        const f16x8 kf = *reinterpret_cast<const f16x8*>(
            Kc + ((slot * 128 + (ks * 16 + hi * 8) * 2) ^ swz(slot)));
        sacc[kt] = __builtin_amdgcn_mfma_f32_32x32x16_f16(kf, qf[ks], sacc[kt], 0, 0, 0);
      }
    }

    // -- mask invalid keys (edge trunks only) ----------------------------
    if (q0 < 48 || q0 > NSEQ - 80) {
      #pragma unroll
      for (int kt = 0; kt < 4; ++kt)
        #pragma unroll
        for (int r = 0; r < 16; ++r) {
          const int key = kb0 + kt * 32 + (r & 3) + 8 * (r >> 2) + 4 * hi;
          if ((unsigned)key >= (unsigned)NSEQ) sacc[kt][r] = -1e30f;
        }
    }

    // -- per-lane softmax (base-2) ---------------------------------------
    float mx = -1e30f;
    #pragma unroll
    for (int kt = 0; kt < 4; ++kt)
      #pragma unroll
      for (int r = 0; r < 16; ++r) mx = fmaxf(mx, sacc[kt][r]);
    mx = fmaxf(mx, __shfl_xor(mx, 32));
    float sum = 0.f;
    #pragma unroll
    for (int kt = 0; kt < 4; ++kt)
      #pragma unroll
      for (int r = 0; r < 16; ++r) {
        const float p = exp2f(sacc[kt][r] - mx);
        sacc[kt][r] = p;
        sum += p;
      }
    sum += __shfl_xor(sum, 32);
    const float inv = 1.0f / sum;

    // -- P -> A-fragments in-register, normalized here -------------------
    f16x8 pa[4][2];
    #pragma unroll
    for (int kt = 0; kt < 4; ++kt) {
      u32 pk[8];
      #pragma unroll
      for (int c = 0; c < 8; ++c)
        pk[c] = pk2(sacc[kt][2 * c] * inv, sacc[kt][2 * c + 1] * inv);
      plswap(pk[0], pk[2]); plswap(pk[1], pk[3]);
      plswap(pk[4], pk[6]); plswap(pk[5], pk[7]);
      union { f16x8 f; u32 u[4]; } f0, f1;
      f0.u[0] = pk[0]; f0.u[1] = pk[1]; f0.u[2] = pk[2]; f0.u[3] = pk[3];
      f1.u[0] = pk[4]; f1.u[1] = pk[5]; f1.u[2] = pk[6]; f1.u[3] = pk[7];
      pa[kt][0] = f0.f;
      pa[kt][1] = f1.f;
    }

    // -- O = P V (32 x 64), V via transpose reads from ring --------------
    const u32 vbase = (u32)(size_t)Vc + (u32)(lane * 8);
    f32x16 oacc[2] = {};
    #pragma unroll
    for (int kt = 0; kt < 4; ++kt) {
      // block16 pair index is always even -> contiguous 4KB, no ring split
      const int b16 = (t * 8 + (wave + kt) * 2) & 15;
      f16x4 tt[8];
      tr8(vbase + (u32)(b16 * 2048), tt);
      union { f16x8 f; f16x4 h2[2]; } b00, b01, b10, b11;
      b00.h2[0] = tt[0]; b00.h2[1] = tt[1];
      b01.h2[0] = tt[2]; b01.h2[1] = tt[3];
      b10.h2[0] = tt[4]; b10.h2[1] = tt[5];
      b11.h2[0] = tt[6]; b11.h2[1] = tt[7];
      oacc[0] = __builtin_amdgcn_mfma_f32_32x32x16_f16(pa[kt][0], b00.f, oacc[0], 0, 0, 0);
      oacc[1] = __builtin_amdgcn_mfma_f32_32x32x16_f16(pa[kt][0], b01.f, oacc[1], 0, 0, 0);
      oacc[0] = __builtin_amdgcn_mfma_f32_32x32x16_f16(pa[kt][1], b10.f, oacc[0], 0, 0, 0);
      oacc[1] = __builtin_amdgcn_mfma_f32_32x32x16_f16(pa[kt][1], b11.f, oacc[1], 0, 0, 0);
    }

    // -- store O ----------------------------------------------------------
    #pragma unroll
    for (int r = 0; r < 16; ++r) {
      const int row = q0 + (r & 3) + 8 * (r >> 2) + 4 * hi;
      float* po = oh + (size_t)row * DHEAD + l31;
      po[0]  = oacc[0][r];
      po[32] = oacc[1][r];
    }

    // -- commit next tile's rows to the ring ------------------------------
    if (t < 3) {
      __syncthreads();                 // all reads of tile t done
      #pragma unroll
      for (int it = 0; it < 4; ++it) {
        const int slot = (rbase + it * 32 + rsub) & RMASK;
        const u32x4 wk = {pk2(sk[it][0].x, sk[it][0].y), pk2(sk[it][0].z, sk[it][0].w),
                          pk2(sk[it][1].x, sk[it][1].y), pk2(sk[it][1].z, sk[it][1].w)};
        *reinterpret_cast<u32x4*>(Kc + ((slot * 128 + c8 * 2) ^ swz(slot))) = wk;
        const u32x4 wv = {pk2(sv[it][0].x, sv[it][0].y), pk2(sv[it][0].z, sv[it][0].w),
                          pk2(sv[it][1].x, sv[it][1].y), pk2(sv[it][1].z, sv[it][1].w)};
        *reinterpret_cast<u32x4*>(Vc + vaddr(slot, c8)) = wv;
      }
      __syncthreads();                 // ring updated for tile t+1
      #pragma unroll
      for (int ks = 0; ks < 4; ++ks) {
        qrA[ks][0] = qrB[ks][0];
        qrA[ks][1] = qrB[ks][1];
      }
    }
  }
}

extern "C" void kernel_launch(void* const* d_in, const int* in_sizes, int n_in,
                              void* d_out, int out_size, void* d_ws, size_t ws_size,
                              hipStream_t stream) {
  const float* q = (const float*)d_in[0];
  const float* k = (const float*)d_in[1];
  const float* v = (const float*)d_in[2];
  float* out = (float*)d_out;
  dim3 grid(512), block(256);   // persistent: 2 blocks/CU, 4 tiles each
  hipLaunchKernelGGL(local_attn_kernel, grid, block, 0, stream, q, k, v, out);
}

// Round 11
// 46.183 us; speedup vs baseline: 1.2843x; 1.0913x over previous
//
#include <hip/hip_runtime.h>
#include <hip/hip_bf16.h>

// Local (trunked) attention, MI355X gfx950.
// B=1, H=16, N=16384, d=64 fp32; 32-query trunks x 128-key window, pad_left=48.
// Block = 4 waves = 4 consecutive trunks of one head; 224-row K/V window union
// staged to LDS as f16. T14 async-stage split: ALL global loads (Q,K,V) issued
// up front; K converted+written -> barrier -> S^T+softmax+P-pack (V loads land
// underneath) -> V converted+written -> barrier -> PV. K: row-major
// XOR-swizzled ds_read_b128. V: 4x16 subtiles via ds_read_b64_tr_b16.
// Swapped-QK^T 32x32 MFMA, per-lane softmax, P normalized in the in-register
// pack (cvt_pkrtz + permlane32_swap).

typedef _Float16 f16x8 __attribute__((ext_vector_type(8)));
typedef _Float16 f16x4 __attribute__((ext_vector_type(4)));
typedef float f32x16 __attribute__((ext_vector_type(16)));
typedef unsigned int u32;
typedef u32 u32x4 __attribute__((ext_vector_type(4)));

#define NSEQ   16384
#define DHEAD  64
#define LOG2E  1.44269504088896340736f
#define TRB    4                 // trunks per block
#define BQ     (TRB * 32)        // 128 queries per block
#define WROWS  (BQ + 96)         // 224 staged rows
#define RSTR   128               // K row stride (bytes, 64 f16)
#define KBYTES (WROWS * RSTR)    // 28672 each for K and V

__device__ __forceinline__ int swz(int r) {
  return ((r & 7) << 4) | ((r & 8) << 3);   // permute 16B-slots within a row
}

__device__ __forceinline__ u32 pk2(float a, float b) {
  auto h2 = __builtin_amdgcn_cvt_pkrtz(a, b);
  return __builtin_bit_cast(u32, h2);
}

__device__ __forceinline__ void plswap(u32& a, u32& b) {
#if __has_builtin(__builtin_amdgcn_permlane32_swap)
  typedef u32 u32x2 __attribute__((ext_vector_type(2)));
  u32x2 r = __builtin_amdgcn_permlane32_swap(a, b, false, false);
  a = r[0]; b = r[1];
#else
  const int hi = (threadIdx.x & 63) >> 5;
  u32 sa = (u32)__shfl_xor((int)a, 32);
  u32 sb = (u32)__shfl_xor((int)b, 32);
  u32 na = hi ? sb : a;
  u32 nb = hi ? b : sa;
  a = na; b = nb;
#endif
}

// 8 transpose-reads (one 32-key tile x full d), one wait.
// va = Vc + pair-of-key16-blocks base + lane*8.
__device__ __forceinline__ void tr8(u32 va, f16x4 (&t)[8]) {
  asm volatile("ds_read_b64_tr_b16 %0, %8 offset:0\n\t"
               "ds_read_b64_tr_b16 %1, %8 offset:1024\n\t"
               "ds_read_b64_tr_b16 %2, %8 offset:512\n\t"
               "ds_read_b64_tr_b16 %3, %8 offset:1536\n\t"
               "ds_read_b64_tr_b16 %4, %8 offset:2048\n\t"
               "ds_read_b64_tr_b16 %5, %8 offset:3072\n\t"
               "ds_read_b64_tr_b16 %6, %8 offset:2560\n\t"
               "ds_read_b64_tr_b16 %7, %8 offset:3584\n\t"
               "s_waitcnt lgkmcnt(0)"
               : "=&v"(t[0]), "=&v"(t[1]), "=&v"(t[2]), "=&v"(t[3]),
                 "=&v"(t[4]), "=&v"(t[5]), "=&v"(t[6]), "=&v"(t[7])
               : "v"(va));
  __builtin_amdgcn_sched_barrier(0);
}

// V subtile byte address (matches tr8's delivery order).
__device__ __forceinline__ int vaddr(int r, int c8) {
  const int dh = c8 >> 4;
  const int idx = ((r >> 2) & 1) * 8 + (dh >> 1) * 4 + ((r >> 3) & 1) * 2 + (dh & 1);
  return (r >> 4) * 2048 + idx * 128 + (r & 3) * 32 + (c8 & 15) * 2;
}

__global__ __launch_bounds__(256, 2) void local_attn_kernel(
    const float* __restrict__ q, const float* __restrict__ k,
    const float* __restrict__ v, float* __restrict__ out) {
  __shared__ __align__(128) char smem[2 * KBYTES];   // 57,344 B: K then V
  char* const Kc = smem;
  char* const Vc = smem + KBYTES;

  const int tid  = threadIdx.x;
  const int wave = tid >> 6;
  const int lane = tid & 63;
  const int l31  = lane & 31;
  const int hi   = lane >> 5;
  const int rsub = tid >> 3;          // 0..31 (stage row-sub)
  const int c8   = (tid & 7) * 8;     // stage f32 col

  int bid = blockIdx.x;
  bid = (bid & 7) * 256 + (bid >> 3);      // XCD swizzle (2048 % 8 == 0)
  const int h   = bid >> 7;                // head
  const int q0b = (bid & 127) << 7;        // block's first query row
  const int kg0 = q0b - 48;                // global row of LDS row 0
  const int q0  = q0b + wave * 32;         // this wave's trunk
  const int kb0 = q0 - 48;                 // wave's window start
  const int kvb = wave * 32;               // wave's local key base in LDS

  const float* __restrict__ qh = q + (size_t)h * NSEQ * DHEAD;
  const float* __restrict__ kh = k + (size_t)h * NSEQ * DHEAD;
  const float* __restrict__ vh = v + (size_t)h * NSEQ * DHEAD;

  // ---- issue ALL global loads up front (deep MLP) -----------------------
  float4 qr[4][2];
  #pragma unroll
  for (int ks = 0; ks < 4; ++ks) {
    const float* p = qh + (size_t)(q0 + l31) * DHEAD + ks * 16 + hi * 8;
    qr[ks][0] = *reinterpret_cast<const float4*>(p);
    qr[ks][1] = *reinterpret_cast<const float4*>(p + 4);
  }
  float4 kr[7][2], vr[7][2];
  #pragma unroll
  for (int it = 0; it < 7; ++it) {
    const int r = it * 32 + rsub;
    const int g = min(max(kg0 + r, 0), NSEQ - 1);   // clamp; masked in S
    const float* pk_ = kh + (size_t)g * DHEAD + c8;
    kr[it][0] = *reinterpret_cast<const float4*>(pk_);
    kr[it][1] = *reinterpret_cast<const float4*>(pk_ + 4);
  }
  #pragma unroll
  for (int it = 0; it < 7; ++it) {
    const int r = it * 32 + rsub;
    const int g = min(max(kg0 + r, 0), NSEQ - 1);
    const float* pv_ = vh + (size_t)g * DHEAD + c8;
    vr[it][0] = *reinterpret_cast<const float4*>(pv_);
    vr[it][1] = *reinterpret_cast<const float4*>(pv_ + 4);
  }

  // ---- convert + write K only (V stays in regs, loads still in flight) --
  #pragma unroll
  for (int it = 0; it < 7; ++it) {
    const int r = it * 32 + rsub;
    const u32x4 w = {pk2(kr[it][0].x, kr[it][0].y), pk2(kr[it][0].z, kr[it][0].w),
                     pk2(kr[it][1].x, kr[it][1].y), pk2(kr[it][1].z, kr[it][1].w)};
    *reinterpret_cast<u32x4*>(Kc + ((r * RSTR + c8 * 2) ^ swz(r))) = w;
  }

  // ---- Q -> f16 fragments (log2e-scaled) --------------------------------
  f16x8 qf[4];
  #pragma unroll
  for (int ks = 0; ks < 4; ++ks) {
    qf[ks][0] = (_Float16)(qr[ks][0].x * LOG2E); qf[ks][1] = (_Float16)(qr[ks][0].y * LOG2E);
    qf[ks][2] = (_Float16)(qr[ks][0].z * LOG2E); qf[ks][3] = (_Float16)(qr[ks][0].w * LOG2E);
    qf[ks][4] = (_Float16)(qr[ks][1].x * LOG2E); qf[ks][5] = (_Float16)(qr[ks][1].y * LOG2E);
    qf[ks][6] = (_Float16)(qr[ks][1].z * LOG2E); qf[ks][7] = (_Float16)(qr[ks][1].w * LOG2E);
  }

  __syncthreads();                       // K staged

  // ---- S^T = K Q^T  (128 keys x 32 queries) -----------------------------
  // D[m=key][n=q]: col = lane&31 = q, row = (r&3)+8*(r>>2)+4*hi (+32*kt)
  f32x16 sacc[4] = {};
  __builtin_amdgcn_s_setprio(1);
  #pragma unroll
  for (int ks = 0; ks < 4; ++ks) {
    #pragma unroll
    for (int kt = 0; kt < 4; ++kt) {
      const int row = kvb + kt * 32 + l31;
      const f16x8 kf = *reinterpret_cast<const f16x8*>(
          Kc + ((row * RSTR + (ks * 16 + hi * 8) * 2) ^ swz(row)));
      sacc[kt] = __builtin_amdgcn_mfma_f32_32x32x16_f16(kf, qf[ks], sacc[kt], 0, 0, 0);
    }
  }
  __builtin_amdgcn_s_setprio(0);

  // ---- mask invalid keys (edge trunks only) -----------------------------
  if (q0 < 48 || q0 > NSEQ - 80) {
    #pragma unroll
    for (int kt = 0; kt < 4; ++kt)
      #pragma unroll
      for (int r = 0; r < 16; ++r) {
        const int key = kb0 + kt * 32 + (r & 3) + 8 * (r >> 2) + 4 * hi;
        if ((unsigned)key >= (unsigned)NSEQ) sacc[kt][r] = -1e30f;
      }
  }

  // ---- per-lane softmax over 128 keys (base-2 domain) -------------------
  float mx = -1e30f;
  #pragma unroll
  for (int kt = 0; kt < 4; ++kt)
    #pragma unroll
    for (int r = 0; r < 16; ++r) mx = fmaxf(mx, sacc[kt][r]);
  mx = fmaxf(mx, __shfl_xor(mx, 32));
  float sum = 0.f;
  #pragma unroll
  for (int kt = 0; kt < 4; ++kt)
    #pragma unroll
    for (int r = 0; r < 16; ++r) {
      const float p = exp2f(sacc[kt][r] - mx);
      sacc[kt][r] = p;
      sum += p;
    }
  sum += __shfl_xor(sum, 32);
  const float inv = 1.0f / sum;

  // ---- P -> A-fragments in-register, normalized HERE --------------------
  // (lane col = query only in the S^T phase; after PV lanes mean d-columns)
  f16x8 pa[4][2];
  #pragma unroll
  for (int kt = 0; kt < 4; ++kt) {
    u32 pk[8];
    #pragma unroll
    for (int c = 0; c < 8; ++c)
      pk[c] = pk2(sacc[kt][2 * c] * inv, sacc[kt][2 * c + 1] * inv);
    plswap(pk[0], pk[2]); plswap(pk[1], pk[3]);
    plswap(pk[4], pk[6]); plswap(pk[5], pk[7]);
    union { f16x8 f; u32 u[4]; } f0, f1;
    f0.u[0] = pk[0]; f0.u[1] = pk[1]; f0.u[2] = pk[2]; f0.u[3] = pk[3];
    f1.u[0] = pk[4]; f1.u[1] = pk[5]; f1.u[2] = pk[6]; f1.u[3] = pk[7];
    pa[kt][0] = f0.f;
    pa[kt][1] = f1.f;
  }

  // ---- convert + write V (loads landed under S^T/softmax) ---------------
  #pragma unroll
  for (int it = 0; it < 7; ++it) {
    const int r = it * 32 + rsub;
    const u32x4 w = {pk2(vr[it][0].x, vr[it][0].y), pk2(vr[it][0].z, vr[it][0].w),
                     pk2(vr[it][1].x, vr[it][1].y), pk2(vr[it][1].z, vr[it][1].w)};
    *reinterpret_cast<u32x4*>(Vc + vaddr(r, c8)) = w;
  }

  __syncthreads();                       // V staged

  // ---- O = P V  (32 x 64), V via hardware transpose reads ---------------
  const u32 vb = (u32)(size_t)Vc + (u32)(lane * 8);
  f32x16 oacc[2] = {};
  __builtin_amdgcn_s_setprio(1);
  #pragma unroll
  for (int kt = 0; kt < 4; ++kt) {
    f16x4 t[8];
    tr8(vb + (u32)(2 * (wave + kt) * 2048), t);
    union { f16x8 f; f16x4 h2[2]; } b00, b01, b10, b11;
    b00.h2[0] = t[0]; b00.h2[1] = t[1];   // keys 0..7 of tile, d 0..31
    b01.h2[0] = t[2]; b01.h2[1] = t[3];   // keys 0..7, d 32..63
    b10.h2[0] = t[4]; b10.h2[1] = t[5];   // keys 8..15, d 0..31
    b11.h2[0] = t[6]; b11.h2[1] = t[7];   // keys 8..15, d 32..63
    oacc[0] = __builtin_amdgcn_mfma_f32_32x32x16_f16(pa[kt][0], b00.f, oacc[0], 0, 0, 0);
    oacc[1] = __builtin_amdgcn_mfma_f32_32x32x16_f16(pa[kt][0], b01.f, oacc[1], 0, 0, 0);
    oacc[0] = __builtin_amdgcn_mfma_f32_32x32x16_f16(pa[kt][1], b10.f, oacc[0], 0, 0, 0);
    oacc[1] = __builtin_amdgcn_mfma_f32_32x32x16_f16(pa[kt][1], b11.f, oacc[1], 0, 0, 0);
  }
  __builtin_amdgcn_s_setprio(0);

  // ---- store O (row = query = crow(r,hi); col = lane = d) ---------------
  float* __restrict__ oh = out + (size_t)h * NSEQ * DHEAD;
  #pragma unroll
  for (int r = 0; r < 16; ++r) {
    const int row = q0 + (r & 3) + 8 * (r >> 2) + 4 * hi;
    float* po = oh + (size_t)row * DHEAD + l31;
    po[0]  = oacc[0][r];
    po[32] = oacc[1][r];
  }
}

extern "C" void kernel_launch(void* const* d_in, const int* in_sizes, int n_in,
                              void* d_out, int out_size, void* d_ws, size_t ws_size,
                              hipStream_t stream) {
  const float* q = (const float*)d_in[0];
  const float* k = (const float*)d_in[1];
  const float* v = (const float*)d_in[2];
  float* out = (float*)d_out;
  dim3 grid(2048), block(256);   // block = 4 consecutive trunks of one head
  hipLaunchKernelGGL(local_attn_kernel, grid, block, 0, stream, q, k, v, out);
}

// Round 13
// 45.721 us; speedup vs baseline: 1.2973x; 1.0101x over previous
//
#include <hip/hip_runtime.h>
#include <hip/hip_bf16.h>

// Local (trunked) attention, MI355X gfx950.
// B=1, H=16, N=16384, d=64 fp32; 32-query trunks x 128-key window, pad_left=48.
// Block = 4 waves = 4 consecutive trunks of one head; 224-row K/V window union
// staged to LDS as f16. T14 async-stage split, enforced via a volatile asm
// memory clobber after the load-issue block: loads (memory reads) cannot sink
// past it, so all Q/K/V loads are issued up front; K is converted/written
// first (counted vmcnt leaves V in flight), S^T+softmax+P-pack run while V
// loads land, then V is converted/written. K: row-major XOR-swizzled
// ds_read_b128. V: 4x16 subtiles via ds_read_b64_tr_b16. Swapped-QK^T 32x32
// MFMA, per-lane softmax, P normalized in the in-register pack.

typedef _Float16 f16x8 __attribute__((ext_vector_type(8)));
typedef _Float16 f16x4 __attribute__((ext_vector_type(4)));
typedef float f32x16 __attribute__((ext_vector_type(16)));
typedef unsigned int u32;
typedef u32 u32x4 __attribute__((ext_vector_type(4)));

#define NSEQ   16384
#define DHEAD  64
#define LOG2E  1.44269504088896340736f
#define TRB    4                 // trunks per block
#define BQ     (TRB * 32)        // 128 queries per block
#define WROWS  (BQ + 96)         // 224 staged rows
#define RSTR   128               // K row stride (bytes, 64 f16)
#define KBYTES (WROWS * RSTR)    // 28672 each for K and V

__device__ __forceinline__ int swz(int r) {
  return ((r & 7) << 4) | ((r & 8) << 3);   // permute 16B-slots within a row
}

__device__ __forceinline__ u32 pk2(float a, float b) {
  auto h2 = __builtin_amdgcn_cvt_pkrtz(a, b);
  return __builtin_bit_cast(u32, h2);
}

__device__ __forceinline__ void plswap(u32& a, u32& b) {
#if __has_builtin(__builtin_amdgcn_permlane32_swap)
  typedef u32 u32x2 __attribute__((ext_vector_type(2)));
  u32x2 r = __builtin_amdgcn_permlane32_swap(a, b, false, false);
  a = r[0]; b = r[1];
#else
  const int hi = (threadIdx.x & 63) >> 5;
  u32 sa = (u32)__shfl_xor((int)a, 32);
  u32 sb = (u32)__shfl_xor((int)b, 32);
  u32 na = hi ? sb : a;
  u32 nb = hi ? b : sa;
  a = na; b = nb;
#endif
}

// 8 transpose-reads (one 32-key tile x full d), one wait.
// va = Vc + pair-of-key16-blocks base + lane*8.
__device__ __forceinline__ void tr8(u32 va, f16x4 (&t)[8]) {
  asm volatile("ds_read_b64_tr_b16 %0, %8 offset:0\n\t"
               "ds_read_b64_tr_b16 %1, %8 offset:1024\n\t"
               "ds_read_b64_tr_b16 %2, %8 offset:512\n\t"
               "ds_read_b64_tr_b16 %3, %8 offset:1536\n\t"
               "ds_read_b64_tr_b16 %4, %8 offset:2048\n\t"
               "ds_read_b64_tr_b16 %5, %8 offset:3072\n\t"
               "ds_read_b64_tr_b16 %6, %8 offset:2560\n\t"
               "ds_read_b64_tr_b16 %7, %8 offset:3584\n\t"
               "s_waitcnt lgkmcnt(0)"
               : "=&v"(t[0]), "=&v"(t[1]), "=&v"(t[2]), "=&v"(t[3]),
                 "=&v"(t[4]), "=&v"(t[5]), "=&v"(t[6]), "=&v"(t[7])
               : "v"(va));
  __builtin_amdgcn_sched_barrier(0);
}

// V subtile byte address (matches tr8's delivery order).
__device__ __forceinline__ int vaddr(int r, int c8) {
  const int dh = c8 >> 4;
  const int idx = ((r >> 2) & 1) * 8 + (dh >> 1) * 4 + ((r >> 3) & 1) * 2 + (dh & 1);
  return (r >> 4) * 2048 + idx * 128 + (r & 3) * 32 + (c8 & 15) * 2;
}

__global__ __launch_bounds__(256, 2) void local_attn_kernel(
    const float* __restrict__ q, const float* __restrict__ k,
    const float* __restrict__ v, float* __restrict__ out) {
  __shared__ __align__(128) char smem[2 * KBYTES];   // 57,344 B: K then V
  char* const Kc = smem;
  char* const Vc = smem + KBYTES;

  const int tid  = threadIdx.x;
  const int wave = tid >> 6;
  const int lane = tid & 63;
  const int l31  = lane & 31;
  const int hi   = lane >> 5;
  const int rsub = tid >> 3;          // 0..31 (stage row-sub)
  const int c8   = (tid & 7) * 8;     // stage f32 col

  int bid = blockIdx.x;
  bid = (bid & 7) * 256 + (bid >> 3);      // XCD swizzle (2048 % 8 == 0)
  const int h   = bid >> 7;                // head
  const int q0b = (bid & 127) << 7;        // block's first query row
  const int kg0 = q0b - 48;                // global row of LDS row 0
  const int q0  = q0b + wave * 32;         // this wave's trunk
  const int kb0 = q0 - 48;                 // wave's window start
  const int kvb = wave * 32;               // wave's local key base in LDS

  const float* __restrict__ qh = q + (size_t)h * NSEQ * DHEAD;
  const float* __restrict__ kh = k + (size_t)h * NSEQ * DHEAD;
  const float* __restrict__ vh = v + (size_t)h * NSEQ * DHEAD;

  // ---- issue ALL global loads up front (deep MLP), then PIN issue order --
  float4 qr[4][2];
  #pragma unroll
  for (int ks = 0; ks < 4; ++ks) {
    const float* p = qh + (size_t)(q0 + l31) * DHEAD + ks * 16 + hi * 8;
    qr[ks][0] = *reinterpret_cast<const float4*>(p);
    qr[ks][1] = *reinterpret_cast<const float4*>(p + 4);
  }
  float4 kr[7][2], vr[7][2];
  #pragma unroll
  for (int it = 0; it < 7; ++it) {
    const int r = it * 32 + rsub;
    const int g = min(max(kg0 + r, 0), NSEQ - 1);   // clamp; masked in S
    const float* pk_ = kh + (size_t)g * DHEAD + c8;
    kr[it][0] = *reinterpret_cast<const float4*>(pk_);
    kr[it][1] = *reinterpret_cast<const float4*>(pk_ + 4);
  }
  #pragma unroll
  for (int it = 0; it < 7; ++it) {
    const int r = it * 32 + rsub;
    const int g = min(max(kg0 + r, 0), NSEQ - 1);
    const float* pv_ = vh + (size_t)g * DHEAD + c8;
    vr[it][0] = *reinterpret_cast<const float4*>(pv_);
    vr[it][1] = *reinterpret_cast<const float4*>(pv_ + 4);
  }
  // No memory op may cross this point: all loads above are ISSUED here,
  // and vr's only uses are after softmax -> results stay live in VGPRs.
  asm volatile("" ::: "memory");

  // ---- convert + write K only (V loads still in flight) -----------------
  #pragma unroll
  for (int it = 0; it < 7; ++it) {
    const int r = it * 32 + rsub;
    const u32x4 w = {pk2(kr[it][0].x, kr[it][0].y), pk2(kr[it][0].z, kr[it][0].w),
                     pk2(kr[it][1].x, kr[it][1].y), pk2(kr[it][1].z, kr[it][1].w)};
    *reinterpret_cast<u32x4*>(Kc + ((r * RSTR + c8 * 2) ^ swz(r))) = w;
  }

  // ---- Q -> f16 fragments (log2e-scaled) --------------------------------
  f16x8 qf[4];
  #pragma unroll
  for (int ks = 0; ks < 4; ++ks) {
    qf[ks][0] = (_Float16)(qr[ks][0].x * LOG2E); qf[ks][1] = (_Float16)(qr[ks][0].y * LOG2E);
    qf[ks][2] = (_Float16)(qr[ks][0].z * LOG2E); qf[ks][3] = (_Float16)(qr[ks][0].w * LOG2E);
    qf[ks][4] = (_Float16)(qr[ks][1].x * LOG2E); qf[ks][5] = (_Float16)(qr[ks][1].y * LOG2E);
    qf[ks][6] = (_Float16)(qr[ks][1].z * LOG2E); qf[ks][7] = (_Float16)(qr[ks][1].w * LOG2E);
  }

  __syncthreads();                       // K staged

  // ---- S^T = K Q^T  (128 keys x 32 queries) -----------------------------
  // D[m=key][n=q]: col = lane&31 = q, row = (r&3)+8*(r>>2)+4*hi (+32*kt)
  f32x16 sacc[4] = {};
  #pragma unroll
  for (int ks = 0; ks < 4; ++ks) {
    #pragma unroll
    for (int kt = 0; kt < 4; ++kt) {
      const int row = kvb + kt * 32 + l31;
      const f16x8 kf = *reinterpret_cast<const f16x8*>(
          Kc + ((row * RSTR + (ks * 16 + hi * 8) * 2) ^ swz(row)));
      sacc[kt] = __builtin_amdgcn_mfma_f32_32x32x16_f16(kf, qf[ks], sacc[kt], 0, 0, 0);
    }
  }

  // ---- mask invalid keys (edge trunks only) -----------------------------
  if (q0 < 48 || q0 > NSEQ - 80) {
    #pragma unroll
    for (int kt = 0; kt < 4; ++kt)
      #pragma unroll
      for (int r = 0; r < 16; ++r) {
        const int key = kb0 + kt * 32 + (r & 3) + 8 * (r >> 2) + 4 * hi;
        if ((unsigned)key >= (unsigned)NSEQ) sacc[kt][r] = -1e30f;
      }
  }

  // ---- per-lane softmax over 128 keys (base-2 domain) -------------------
  float mx = -1e30f;
  #pragma unroll
  for (int kt = 0; kt < 4; ++kt)
    #pragma unroll
    for (int r = 0; r < 16; ++r) mx = fmaxf(mx, sacc[kt][r]);
  mx = fmaxf(mx, __shfl_xor(mx, 32));
  float sum = 0.f;
  #pragma unroll
  for (int kt = 0; kt < 4; ++kt)
    #pragma unroll
    for (int r = 0; r < 16; ++r) {
      const float p = exp2f(sacc[kt][r] - mx);
      sacc[kt][r] = p;
      sum += p;
    }
  sum += __shfl_xor(sum, 32);
  const float inv = 1.0f / sum;

  // ---- P -> A-fragments in-register, normalized HERE --------------------
  // (lane col = query only in the S^T phase; after PV lanes mean d-columns)
  f16x8 pa[4][2];
  #pragma unroll
  for (int kt = 0; kt < 4; ++kt) {
    u32 pk[8];
    #pragma unroll
    for (int c = 0; c < 8; ++c)
      pk[c] = pk2(sacc[kt][2 * c] * inv, sacc[kt][2 * c + 1] * inv);
    plswap(pk[0], pk[2]); plswap(pk[1], pk[3]);
    plswap(pk[4], pk[6]); plswap(pk[5], pk[7]);
    union { f16x8 f; u32 u[4]; } f0, f1;
    f0.u[0] = pk[0]; f0.u[1] = pk[1]; f0.u[2] = pk[2]; f0.u[3] = pk[3];
    f1.u[0] = pk[4]; f1.u[1] = pk[5]; f1.u[2] = pk[6]; f1.u[3] = pk[7];
    pa[kt][0] = f0.f;
    pa[kt][1] = f1.f;
  }

  // ---- convert + write V (loads landed under S^T/softmax) ---------------
  #pragma unroll
  for (int it = 0; it < 7; ++it) {
    const int r = it * 32 + rsub;
    const u32x4 w = {pk2(vr[it][0].x, vr[it][0].y), pk2(vr[it][0].z, vr[it][0].w),
                     pk2(vr[it][1].x, vr[it][1].y), pk2(vr[it][1].z, vr[it][1].w)};
    *reinterpret_cast<u32x4*>(Vc + vaddr(r, c8)) = w;
  }

  __syncthreads();                       // V staged

  // ---- O = P V  (32 x 64), V via hardware transpose reads ---------------
  const u32 vb = (u32)(size_t)Vc + (u32)(lane * 8);
  f32x16 oacc[2] = {};
  #pragma unroll
  for (int kt = 0; kt < 4; ++kt) {
    f16x4 t[8];
    tr8(vb + (u32)(2 * (wave + kt) * 2048), t);
    union { f16x8 f; f16x4 h2[2]; } b00, b01, b10, b11;
    b00.h2[0] = t[0]; b00.h2[1] = t[1];   // keys 0..7 of tile, d 0..31
    b01.h2[0] = t[2]; b01.h2[1] = t[3];   // keys 0..7, d 32..63
    b10.h2[0] = t[4]; b10.h2[1] = t[5];   // keys 8..15, d 0..31
    b11.h2[0] = t[6]; b11.h2[1] = t[7];   // keys 8..15, d 32..63
    oacc[0] = __builtin_amdgcn_mfma_f32_32x32x16_f16(pa[kt][0], b00.f, oacc[0], 0, 0, 0);
    oacc[1] = __builtin_amdgcn_mfma_f32_32x32x16_f16(pa[kt][0], b01.f, oacc[1], 0, 0, 0);
    oacc[0] = __builtin_amdgcn_mfma_f32_32x32x16_f16(pa[kt][1], b10.f, oacc[0], 0, 0, 0);
    oacc[1] = __builtin_amdgcn_mfma_f32_32x32x16_f16(pa[kt][1], b11.f, oacc[1], 0, 0, 0);
  }

  // ---- store O (row = query = crow(r,hi); col = lane = d) ---------------
  float* __restrict__ oh = out + (size_t)h * NSEQ * DHEAD;
  #pragma unroll
  for (int r = 0; r < 16; ++r) {
    const int row = q0 + (r & 3) + 8 * (r >> 2) + 4 * hi;
    float* po = oh + (size_t)row * DHEAD + l31;
    po[0]  = oacc[0][r];
    po[32] = oacc[1][r];
  }
}

extern "C" void kernel_launch(void* const* d_in, const int* in_sizes, int n_in,
                              void* d_out, int out_size, void* d_ws, size_t ws_size,
                              hipStream_t stream) {
  const float* q = (const float*)d_in[0];
  const float* k = (const float*)d_in[1];
  const float* v = (const float*)d_in[2];
  float* out = (float*)d_out;
  dim3 grid(2048), block(256);   // block = 4 consecutive trunks of one head
  hipLaunchKernelGGL(local_attn_kernel, grid, block, 0, stream, q, k, v, out);
}